// Round 10
// baseline (206.153 us; speedup 1.0000x reference)
//
#include <hip/hip_runtime.h>

#define N_NODES 100000
#define N_EDGES 3200000
#define N_GRAPHS 1024
#define NCLS 21
#define NBKT 391          // buckets of 256 nodes (391*256 = 100096)
#define CAP 8960          // padded bucket capacity (mean 8192, sigma 90 -> +8.5 sigma)
#define NB 512            // streaming blocks for binning
#define CHUNK 6250        // N_EDGES / NB
#define TROW 72           // LDS tile row stride in ushorts (144B: breaks b128 bank aliasing)

typedef short s8v __attribute__((ext_vector_type(8)));
typedef float f4v __attribute__((ext_vector_type(4)));
typedef float f2v __attribute__((ext_vector_type(2)));

__device__ __forceinline__ float bf2f(unsigned short u) {
    return __uint_as_float(((unsigned)u) << 16);
}
__device__ __forceinline__ unsigned short f2bf(float f) {
    unsigned u = __float_as_uint(f);
    unsigned r = 0x7fffu + ((u >> 16) & 1u);   // RNE
    return (unsigned short)((u + r) >> 16);
}
__device__ __forceinline__ f2v max2(f2v v) {
    f2v r; r.x = fmaxf(v.x, 0.0f); r.y = fmaxf(v.y, 0.0f); return r;
}

// ---- fused prep: wp pack (blocks 0-31), gstart (32-36), gcur init (37) ----
__global__ void k_prep(const float* __restrict__ W2l, const float* __restrict__ W2r,
                       unsigned short* __restrict__ wp,
                       const int* __restrict__ batch, int* __restrict__ gstart,
                       int* __restrict__ gcur) {
    if (blockIdx.x < 32) {
        int tid = blockIdx.x * 256 + threadIdx.x;   // 8192 total
        int frag = tid >> 9;
        int r = tid & 511;
        int L = r >> 3, j = r & 7;
        int kstep = frag >> 2, nt = frag & 3;
        int k = kstep * 32 + (L >> 4) * 8 + j;
        int n = nt * 16 + (L & 15);
        float val = (k < 64) ? W2l[k * 64 + n] : W2r[(k - 64) * 64 + n];
        wp[tid] = f2bf(val);
    } else if (blockIdx.x < 37) {
        int g = (blockIdx.x - 32) * 256 + threadIdx.x;
        if (g > N_GRAPHS) return;
        if (g == N_GRAPHS) { gstart[N_GRAPHS] = N_NODES; return; }
        int lo = 0, hi = N_NODES;
        while (lo < hi) { int m = (lo + hi) >> 1; if (batch[m] < g) lo = m + 1; else hi = m; }
        gstart[g] = lo;
    } else {
        for (int i = threadIdx.x; i < NBKT; i += 256) gcur[i] = i * CAP;
    }
}

// ---- single-pass bin: LDS count -> global run reservation -> LDS scatter.
// 256-node buckets: each block's run per bucket is ~16 edges = one FULL 64 B
// line -> single-writer lines, no cross-XCD partial-line RFO sharing. ----
__global__ __launch_bounds__(256) void k_binone(const int* __restrict__ src,
                                                const int* __restrict__ dst,
                                                int* __restrict__ gcur,
                                                unsigned int* __restrict__ bins) {
    __shared__ unsigned int ebuf[CHUNK];         // 25 KB
    __shared__ unsigned short bbuf[CHUNK];       // 12.5 KB
    __shared__ int lh[NBKT];                     // 1.6 KB
    int t = threadIdx.x;
    for (int i = t; i < NBKT; i += 256) lh[i] = 0;
    __syncthreads();
    const int2* s2 = (const int2*)(src + blockIdx.x * CHUNK);
    const int2* d2 = (const int2*)(dst + blockIdx.x * CHUNK);
    for (int i = t; i < CHUNK / 2; i += 256) {
        int2 s = s2[i];
        int2 d = d2[i];
        uint2 pp;
        pp.x = ((unsigned)s.x << 8) | (unsigned)(d.x & 255);
        pp.y = ((unsigned)s.y << 8) | (unsigned)(d.y & 255);
        *(uint2*)(&ebuf[2 * i]) = pp;
        bbuf[2 * i]     = (unsigned short)(d.x >> 8);
        bbuf[2 * i + 1] = (unsigned short)(d.y >> 8);
        atomicAdd(&lh[d.x >> 8], 1);
        atomicAdd(&lh[d.y >> 8], 1);
    }
    __syncthreads();
    // reserve bucket runs; thread owning index i does count->base in place
    for (int i = t; i < NBKT; i += 256) {
        int c = lh[i];
        lh[i] = (c > 0) ? atomicAdd(&gcur[i], c) : 0;
    }
    __syncthreads();
    for (int i = t; i < CHUNK; i += 256) {
        int b = (int)bbuf[i];
        int pos = atomicAdd(&lh[b], 1);
        if (pos < (b + 1) * CAP) bins[pos] = ebuf[i];
    }
}

// ---- per-bucket (256 nodes, 512 threads): slurp -> hist -> scan -> scatter ->
// per-slot contiguous x-sum (no float atomics) -> row/deg + ax. ----
__global__ __launch_bounds__(512) void k_build(
    const int* __restrict__ gcur, unsigned int* __restrict__ bins,
    int* __restrict__ row, unsigned short* __restrict__ deg,
    const float* __restrict__ x, float2* __restrict__ ax) {
    __shared__ unsigned int ebuf[CAP];   // 35 KB
    __shared__ int hist[256];
    __shared__ int curs[256];
    __shared__ int lds[256];
    __shared__ float t1h[256];
    int k = blockIdx.x, t = threadIdx.x;
    int e0 = k * CAP;
    int cnt = min(gcur[k] - e0, CAP);
    if (t < 256) hist[t] = 0;
    __syncthreads();
    for (int i = t; i < cnt; i += 512) {
        unsigned p = bins[e0 + i];
        ebuf[i] = p;
        atomicAdd(&hist[p & 255u], 1);
    }
    __syncthreads();
    if (t < 256) lds[t] = hist[t];
    __syncthreads();
    for (int off = 1; off < 256; off <<= 1) {
        int cur = (t < 256) ? lds[t] : 0;
        int add = (t < 256 && t >= off) ? lds[t - off] : 0;
        __syncthreads();
        if (t < 256) lds[t] = cur + add;
        __syncthreads();
    }
    if (t < 256) {
        int run = e0 + lds[t] - hist[t];
        curs[t] = run;
        int n = k * 256 + t;
        if (n < N_NODES) { row[n] = run; deg[n] = (unsigned short)hist[t]; }
    }
    __syncthreads();
    // scatter: short chain (LDS read -> cursor atomic -> global write), no gather
    for (int i = t; i < cnt; i += 512) {
        unsigned p = ebuf[i];
        int slot = (int)(p & 255u);
        int pos = atomicAdd(&curs[slot], 1);
        bins[pos] = p >> 8;
    }
    __syncthreads();
    // pass 3: per-slot x-sum over the now-contiguous CSR run. 2 threads/slot,
    // stride-2 interleave, 4-wide ILP batches (independent bins+x loads).
    {
        int slot = t >> 1, half = t & 1;
        int start = e0 + lds[slot] - hist[slot];
        int d = hist[slot];
        float s = 0.0f;
        int i = half;
        for (; i + 8 <= d; i += 8) {
            int a0 = bins[start + i];
            int a1 = bins[start + i + 2];
            int a2 = bins[start + i + 4];
            int a3 = bins[start + i + 6];
            float y0 = x[a0], y1 = x[a1], y2 = x[a2], y3 = x[a3];
            s += (y0 + y1) + (y2 + y3);
        }
        for (; i < d; i += 2) s += x[bins[start + i]];
        if (half) t1h[slot] = s;
        __syncthreads();
        if (!half) {
            int n = k * 256 + slot;
            if (n < N_NODES) {
                float tot = s + t1h[slot];
                float a = tot / fmaxf((float)d, 1.0f);
                float2 v; v.x = a; v.y = x[n];
                ax[n] = v;
            }
        }
    }
}

// ---- layer 2 FUSED: gather (agg1,x) pairs -> reconstruct h1 rows in-register
// -> LDS tile -> MFMA GEMV -> h2b.
// h1[s][f] = relu(agg1[s]*W1l[f] + b1[f] + x[s]*W1r[f]) — 8 B gathered per edge;
// gather working set = 800 KB (per-XCD-L2 resident). Each 8-lane group owns ONE
// node (2 passes); lane fo covers features fo*8..fo*8+7. Pair pipeline is
// 2 chunks deep (~580 cyc cover vs ~200-400 cyc L2 latency). ----
__global__ __launch_bounds__(256) void k_l2f(
    const int* __restrict__ row, const unsigned short* __restrict__ deg,
    const unsigned int* __restrict__ csr,
    const float2* __restrict__ ax,
    const float* __restrict__ W1l, const float* __restrict__ b1,
    const float* __restrict__ W1r,
    const unsigned short* __restrict__ wp, const float* __restrict__ b2,
    unsigned short* __restrict__ h2b) {
    __shared__ unsigned short tile[4][16 * TROW];   // 9 KB
    int wid = threadIdx.x >> 6;
    int w = blockIdx.x * 4 + wid;
    if (w >= N_NODES / 16) return;
    int L = threadIdx.x & 63;
    int fo = L & 7;
    int g  = L >> 3;
    unsigned short* tw = tile[wid];

    // per-lane W1 constants for features fo*8 .. fo*8+7, as float2 pairs
    f2v w1l_[4], w1r_[4], bb_[4];
    {
        const f2v* pl = (const f2v*)(W1l + fo * 8);
        const f2v* pr = (const f2v*)(W1r + fo * 8);
        const f2v* pb = (const f2v*)(b1  + fo * 8);
#pragma unroll
        for (int q = 0; q < 4; q++) { w1l_[q] = pl[q]; w1r_[q] = pr[q]; bb_[q] = pb[q]; }
    }

    int nA = w * 16 + g;
    int nB = nA + 8;
    int r0A = row[nA]; int dnA = (int)deg[nA];
    int r0B = row[nB]; int dnB = (int)deg[nB];

// ds_swizzle BitMode: and=0x18 keeps group base (bits 3-4 within 32-half),
// or=j selects lane j of the group. Pattern must be a Sema-time literal.
#define SWZ(v, j) __builtin_amdgcn_ds_swizzle((v), (((j) << 5) | 0x18))
#define EDGE(j) { \
    unsigned au = (unsigned)SWZ((int)__float_as_uint(pr0.x), j); \
    unsigned xu = (unsigned)SWZ((int)__float_as_uint(pr0.y), j); \
    float a_ = __uint_as_float(au), x_ = __uint_as_float(xu); \
    f2v av; av.x = a_; av.y = a_; \
    f2v xv; xv.x = x_; xv.y = x_; \
    pp0 += max2(av * w1l_[0] + (xv * w1r_[0] + bb_[0])); \
    pp1 += max2(av * w1l_[1] + (xv * w1r_[1] + bb_[1])); \
    pp2 += max2(av * w1l_[2] + (xv * w1r_[2] + bb_[2])); \
    pp3 += max2(av * w1l_[3] + (xv * w1r_[3] + bb_[3])); }
#define REM(j) if ((j) < rem) EDGE(j)
#define CLMP(o) max(min(base + (o) + fo, r1 - 1), r0)

#pragma unroll
    for (int pass = 0; pass < 2; pass++) {
        int r0 = pass ? r0B : r0A;
        int dn = pass ? dnB : dnA;
        int trow = g + 8 * pass;
        int r1 = r0 + dn;
        f2v pp0 = {0.f, 0.f}, pp1 = pp0, pp2 = pp0, pp3 = pp0;
        int base = r0;
        // pipeline startup: pairs for chunks 0,1 in flight; index for chunk 2
        unsigned i0 = min((unsigned)csr[CLMP(0)], (unsigned)(N_NODES - 1));
        float2 pr0 = ax[i0];
        unsigned i1 = min((unsigned)csr[CLMP(8)], (unsigned)(N_NODES - 1));
        float2 pr1 = ax[i1];
        unsigned i2 = min((unsigned)csr[CLMP(16)], (unsigned)(N_NODES - 1));
        while (base + 8 <= r1) {
            float2 pr2 = ax[i2];                  // pair for chunk m+2
            unsigned i3 = min((unsigned)csr[CLMP(24)], (unsigned)(N_NODES - 1));
            EDGE(0) EDGE(1) EDGE(2) EDGE(3)
            EDGE(4) EDGE(5) EDGE(6) EDGE(7)
            pr0 = pr1; pr1 = pr2; i2 = i3;
            base += 8;
        }
        int rem = r1 - base;
        if (rem > 0) {
            REM(0) REM(1) REM(2) REM(3)
            REM(4) REM(5) REM(6) REM(7)
        }
        float inv = 1.0f / fmaxf((float)dn, 1.0f);
        f2v iv; iv.x = inv; iv.y = inv;
        pp0 *= iv; pp1 *= iv; pp2 *= iv; pp3 *= iv;
        unsigned w0 = (unsigned)f2bf(pp0.x) | ((unsigned)f2bf(pp0.y) << 16);
        unsigned w1 = (unsigned)f2bf(pp1.x) | ((unsigned)f2bf(pp1.y) << 16);
        unsigned w2 = (unsigned)f2bf(pp2.x) | ((unsigned)f2bf(pp2.y) << 16);
        unsigned w3 = (unsigned)f2bf(pp3.x) | ((unsigned)f2bf(pp3.y) << 16);
        uint4 pk; pk.x = w0; pk.y = w1; pk.z = w2; pk.w = w3;
        *(uint4*)(tw + trow * TROW + fo * 8) = pk;   // full 128B row per group
    }
#undef SWZ
#undef EDGE
#undef REM
#undef CLMP

    // ---- MFMA phase: A = [agg2 (LDS tile) | root h1 (reconstructed)] ----
    int m = L & 15, q = L >> 4;
    int nrow = w * 16 + m;

    const s8v a0 = *(const s8v*)(tw + m * TROW + q * 8);
    const s8v a1 = *(const s8v*)(tw + m * TROW + 32 + q * 8);

    // reconstruct root h1[nrow] slices: features q*8..+7 and 32+q*8..+7
    float2 axn = ax[nrow];
    union { s8v v; unsigned u[4]; } A2, A3;
    {
        const f2v* l1 = (const f2v*)(W1l + q * 8);
        const f2v* r1p = (const f2v*)(W1r + q * 8);
        const f2v* bp = (const f2v*)(b1 + q * 8);
        const f2v* l2 = (const f2v*)(W1l + 32 + q * 8);
        const f2v* r2p = (const f2v*)(W1r + 32 + q * 8);
        const f2v* b2p = (const f2v*)(b1 + 32 + q * 8);
        f2v av; av.x = axn.x; av.y = axn.x;
        f2v xv; xv.x = axn.y; xv.y = axn.y;
#pragma unroll
        for (int k = 0; k < 4; k++) {
            f2v v1 = max2(av * l1[k] + (xv * r1p[k] + bp[k]));
            f2v v2 = max2(av * l2[k] + (xv * r2p[k] + b2p[k]));
            A2.u[k] = (unsigned)f2bf(v1.x) | ((unsigned)f2bf(v1.y) << 16);
            A3.u[k] = (unsigned)f2bf(v2.x) | ((unsigned)f2bf(v2.y) << 16);
        }
    }
    const s8v a2 = A2.v;
    const s8v a3 = A3.v;

#define LOADB(i) s8v B##i = *(const s8v*)(wp + (i) * 512 + L * 8)
    LOADB(0); LOADB(1); LOADB(2); LOADB(3);
    LOADB(4); LOADB(5); LOADB(6); LOADB(7);
    LOADB(8); LOADB(9); LOADB(10); LOADB(11);
    LOADB(12); LOADB(13); LOADB(14); LOADB(15);
#undef LOADB

    f4v acc0 = {0.f, 0.f, 0.f, 0.f}, acc1 = acc0, acc2 = acc0, acc3 = acc0;
    acc0 = __builtin_amdgcn_mfma_f32_16x16x32_bf16(a0, B0,  acc0, 0, 0, 0);
    acc0 = __builtin_amdgcn_mfma_f32_16x16x32_bf16(a1, B4,  acc0, 0, 0, 0);
    acc0 = __builtin_amdgcn_mfma_f32_16x16x32_bf16(a2, B8,  acc0, 0, 0, 0);
    acc0 = __builtin_amdgcn_mfma_f32_16x16x32_bf16(a3, B12, acc0, 0, 0, 0);
    acc1 = __builtin_amdgcn_mfma_f32_16x16x32_bf16(a0, B1,  acc1, 0, 0, 0);
    acc1 = __builtin_amdgcn_mfma_f32_16x16x32_bf16(a1, B5,  acc1, 0, 0, 0);
    acc1 = __builtin_amdgcn_mfma_f32_16x16x32_bf16(a2, B9,  acc1, 0, 0, 0);
    acc1 = __builtin_amdgcn_mfma_f32_16x16x32_bf16(a3, B13, acc1, 0, 0, 0);
    acc2 = __builtin_amdgcn_mfma_f32_16x16x32_bf16(a0, B2,  acc2, 0, 0, 0);
    acc2 = __builtin_amdgcn_mfma_f32_16x16x32_bf16(a1, B6,  acc2, 0, 0, 0);
    acc2 = __builtin_amdgcn_mfma_f32_16x16x32_bf16(a2, B10, acc2, 0, 0, 0);
    acc2 = __builtin_amdgcn_mfma_f32_16x16x32_bf16(a3, B14, acc2, 0, 0, 0);
    acc3 = __builtin_amdgcn_mfma_f32_16x16x32_bf16(a0, B3,  acc3, 0, 0, 0);
    acc3 = __builtin_amdgcn_mfma_f32_16x16x32_bf16(a1, B7,  acc3, 0, 0, 0);
    acc3 = __builtin_amdgcn_mfma_f32_16x16x32_bf16(a2, B11, acc3, 0, 0, 0);
    acc3 = __builtin_amdgcn_mfma_f32_16x16x32_bf16(a3, B15, acc3, 0, 0, 0);

    int fcol = L & 15;
    float bia0 = b2[fcol], bia1 = b2[16 + fcol], bia2 = b2[32 + fcol], bia3 = b2[48 + fcol];
    int rbase = w * 16 + q * 4;
#pragma unroll
    for (int r = 0; r < 4; r++) {
        size_t o = (size_t)(rbase + r) * 64 + fcol;
        h2b[o]      = f2bf(fmaxf(acc0[r] + bia0, 0.0f));
        h2b[o + 16] = f2bf(fmaxf(acc1[r] + bia1, 0.0f));
        h2b[o + 32] = f2bf(fmaxf(acc2[r] + bia2, 0.0f));
        h2b[o + 48] = f2bf(fmaxf(acc3[r] + bia3, 0.0f));
    }
}

// ---- head: block per graph — pool h2 rows + classify, no global intermediates ----
__global__ __launch_bounds__(256) void k_head(
    const unsigned short* __restrict__ h2b, const int* __restrict__ gstart,
    const float* __restrict__ Wc, const float* __restrict__ bc,
    float* __restrict__ out) {
    __shared__ float part[4][64];
    __shared__ float rowv[64];
    int g = blockIdx.x;
    int wid = threadIdx.x >> 6;
    int f = threadIdx.x & 63;
    int ns = gstart[g], ne = gstart[g + 1];
    float s = 0.0f;
    int n = ns + wid;
    for (; n + 12 < ne; n += 16) {
        float v0 = bf2f(h2b[(size_t)(n)      * 64 + f]);
        float v1 = bf2f(h2b[(size_t)(n + 4)  * 64 + f]);
        float v2 = bf2f(h2b[(size_t)(n + 8)  * 64 + f]);
        float v3 = bf2f(h2b[(size_t)(n + 12) * 64 + f]);
        s += (v0 + v1) + (v2 + v3);
    }
    for (; n < ne; n += 4) s += bf2f(h2b[(size_t)n * 64 + f]);
    part[wid][f] = s;
    __syncthreads();
    if (threadIdx.x < 64) {
        float tot = part[0][f] + part[1][f] + part[2][f] + part[3][f];
        rowv[f] = tot / fmaxf((float)(ne - ns), 1.0f);
    }
    __syncthreads();
    if (threadIdx.x < NCLS) {
        float acc = bc[threadIdx.x];
#pragma unroll
        for (int kk = 0; kk < 64; kk++) acc += rowv[kk] * Wc[kk * NCLS + threadIdx.x];
        out[g * NCLS + threadIdx.x] = acc;
    }
}

extern "C" void kernel_launch(void* const* d_in, const int* in_sizes, int n_in,
                              void* d_out, int out_size, void* d_ws, size_t ws_size,
                              hipStream_t stream) {
    const float* x     = (const float*)d_in[0];
    const int*   eidx  = (const int*)d_in[1];
    const int*   batch = (const int*)d_in[2];
    const float* W1l   = (const float*)d_in[3];
    const float* b1    = (const float*)d_in[4];
    const float* W1r   = (const float*)d_in[5];
    const float* W2l   = (const float*)d_in[6];
    const float* b2    = (const float*)d_in[7];
    const float* W2r   = (const float*)d_in[8];
    const float* Wc    = (const float*)d_in[9];
    const float* bc    = (const float*)d_in[10];
    float* out = (float*)d_out;

    const int* src = eidx;
    const int* dst = eidx + N_EDGES;

    // workspace ≈ 28.6 MB
    char* p = (char*)d_ws;
    unsigned int* bins  = (unsigned int*)p;     p += (size_t)NBKT * CAP * 4;     // 14.0 MB
    float2* ax          = (float2*)p;           p += (size_t)N_NODES * 8;        // 0.80 MB
    unsigned short* h2b = (unsigned short*)p;   p += (size_t)N_NODES * 64 * 2;   // 12.8 MB
    int* row   = (int*)p;                       p += (size_t)(N_NODES + 1) * 4;  // 0.40 MB
    unsigned short* deg = (unsigned short*)p;   p += (size_t)N_NODES * 2;        // 0.20 MB
    int* gcur  = (int*)p;                       p += NBKT * 4;
    int* gstart= (int*)p;                       p += (N_GRAPHS + 1) * 4;
    unsigned short* wp = (unsigned short*)p;    p += 8192 * 2;                   // 16 KB

    k_prep  <<<38, 256, 0, stream>>>(W2l, W2r, wp, batch, gstart, gcur);
    k_binone<<<NB, 256, 0, stream>>>(src, dst, gcur, bins);
    k_build <<<NBKT, 512, 0, stream>>>(gcur, bins, row, deg, x, ax);
    k_l2f   <<<(N_NODES / 16 + 3) / 4, 256, 0, stream>>>(row, deg, bins, ax,
                                                          W1l, b1, W1r, wp, b2, h2b);
    k_head  <<<N_GRAPHS, 256, 0, stream>>>(h2b, gstart, Wc, bc, out);
}

// Round 11
// 200.939 us; speedup vs baseline: 1.0259x; 1.0259x over previous
//
#include <hip/hip_runtime.h>

#define N_NODES 100000
#define N_EDGES 3200000
#define N_GRAPHS 1024
#define NCLS 21
#define NBKT 391          // buckets of 256 nodes (391*256 = 100096)
#define CAP 8960          // padded bucket capacity (mean 8192, sigma 90 -> +8.5 sigma)
#define NB 512            // streaming blocks for binning
#define CHUNK 6250        // N_EDGES / NB
#define TROW 72           // LDS tile row stride in ushorts (144B: breaks b128 bank aliasing)

typedef short s8v __attribute__((ext_vector_type(8)));
typedef float f4v __attribute__((ext_vector_type(4)));
typedef float f2v __attribute__((ext_vector_type(2)));

__device__ __forceinline__ float bf2f(unsigned short u) {
    return __uint_as_float(((unsigned)u) << 16);
}
__device__ __forceinline__ unsigned short f2bf(float f) {
    unsigned u = __float_as_uint(f);
    unsigned r = 0x7fffu + ((u >> 16) & 1u);   // RNE
    return (unsigned short)((u + r) >> 16);
}
__device__ __forceinline__ f2v max2(f2v v) {
    f2v r; r.x = fmaxf(v.x, 0.0f); r.y = fmaxf(v.y, 0.0f); return r;
}

// ---- fused prep: wp pack (blocks 0-31), gstart (32-36), gcur init (37) ----
__global__ void k_prep(const float* __restrict__ W2l, const float* __restrict__ W2r,
                       unsigned short* __restrict__ wp,
                       const int* __restrict__ batch, int* __restrict__ gstart,
                       int* __restrict__ gcur) {
    if (blockIdx.x < 32) {
        int tid = blockIdx.x * 256 + threadIdx.x;   // 8192 total
        int frag = tid >> 9;
        int r = tid & 511;
        int L = r >> 3, j = r & 7;
        int kstep = frag >> 2, nt = frag & 3;
        int k = kstep * 32 + (L >> 4) * 8 + j;
        int n = nt * 16 + (L & 15);
        float val = (k < 64) ? W2l[k * 64 + n] : W2r[(k - 64) * 64 + n];
        wp[tid] = f2bf(val);
    } else if (blockIdx.x < 37) {
        int g = (blockIdx.x - 32) * 256 + threadIdx.x;
        if (g > N_GRAPHS) return;
        if (g == N_GRAPHS) { gstart[N_GRAPHS] = N_NODES; return; }
        int lo = 0, hi = N_NODES;
        while (lo < hi) { int m = (lo + hi) >> 1; if (batch[m] < g) lo = m + 1; else hi = m; }
        gstart[g] = lo;
    } else {
        for (int i = threadIdx.x; i < NBKT; i += 256) gcur[i] = i * CAP;
    }
}

// ---- single-pass bin: LDS count -> global run reservation -> LDS scatter.
// 256-node buckets: each block's run per bucket is ~16 edges = one FULL 64 B
// line -> single-writer lines, no cross-XCD partial-line RFO sharing. ----
__global__ __launch_bounds__(256) void k_binone(const int* __restrict__ src,
                                                const int* __restrict__ dst,
                                                int* __restrict__ gcur,
                                                unsigned int* __restrict__ bins) {
    __shared__ unsigned int ebuf[CHUNK];         // 25 KB
    __shared__ unsigned short bbuf[CHUNK];       // 12.5 KB
    __shared__ int lh[NBKT];                     // 1.6 KB
    int t = threadIdx.x;
    for (int i = t; i < NBKT; i += 256) lh[i] = 0;
    __syncthreads();
    const int2* s2 = (const int2*)(src + blockIdx.x * CHUNK);
    const int2* d2 = (const int2*)(dst + blockIdx.x * CHUNK);
    for (int i = t; i < CHUNK / 2; i += 256) {
        int2 s = s2[i];
        int2 d = d2[i];
        uint2 pp;
        pp.x = ((unsigned)s.x << 8) | (unsigned)(d.x & 255);
        pp.y = ((unsigned)s.y << 8) | (unsigned)(d.y & 255);
        *(uint2*)(&ebuf[2 * i]) = pp;
        bbuf[2 * i]     = (unsigned short)(d.x >> 8);
        bbuf[2 * i + 1] = (unsigned short)(d.y >> 8);
        atomicAdd(&lh[d.x >> 8], 1);
        atomicAdd(&lh[d.y >> 8], 1);
    }
    __syncthreads();
    // reserve bucket runs; thread owning index i does count->base in place
    for (int i = t; i < NBKT; i += 256) {
        int c = lh[i];
        lh[i] = (c > 0) ? atomicAdd(&gcur[i], c) : 0;
    }
    __syncthreads();
    for (int i = t; i < CHUNK; i += 256) {
        int b = (int)bbuf[i];
        int pos = atomicAdd(&lh[b], 1);
        if (pos < (b + 1) * CAP) bins[pos] = ebuf[i];
    }
}

// ---- per-bucket (256 nodes, 512 threads): slurp -> hist -> scan -> row/deg +
// CSR re-sort + ax.  ax[n] = (agg1[n], x[n]). ----
__global__ __launch_bounds__(512) void k_build(
    const int* __restrict__ gcur, unsigned int* __restrict__ bins,
    int* __restrict__ row, unsigned short* __restrict__ deg,
    const float* __restrict__ x, float2* __restrict__ ax) {
    __shared__ unsigned int ebuf[CAP];   // 35 KB
    __shared__ int hist[256];
    __shared__ int curs[256];
    __shared__ int lds[256];
    __shared__ float t1[256];
    int k = blockIdx.x, t = threadIdx.x;
    int e0 = k * CAP;
    int cnt = min(gcur[k] - e0, CAP);
    if (t < 256) { hist[t] = 0; t1[t] = 0.0f; }
    __syncthreads();
    for (int i = t; i < cnt; i += 512) {
        unsigned p = bins[e0 + i];
        ebuf[i] = p;
        atomicAdd(&hist[p & 255u], 1);
    }
    __syncthreads();
    if (t < 256) lds[t] = hist[t];
    __syncthreads();
    for (int off = 1; off < 256; off <<= 1) {
        int cur = (t < 256) ? lds[t] : 0;
        int add = (t < 256 && t >= off) ? lds[t - off] : 0;
        __syncthreads();
        if (t < 256) lds[t] = cur + add;
        __syncthreads();
    }
    if (t < 256) {
        int run = e0 + lds[t] - hist[t];
        curs[t] = run;
        int n = k * 256 + t;
        if (n < N_NODES) { row[n] = run; deg[n] = (unsigned short)hist[t]; }
    }
    __syncthreads();
    for (int i = t; i < cnt; i += 512) {
        unsigned p = ebuf[i];
        int slot = (int)(p & 255u);
        int pos = atomicAdd(&curs[slot], 1);
        bins[pos] = p >> 8;
        atomicAdd(&t1[slot], x[p >> 8]);
    }
    __syncthreads();
    if (t < 256) {
        int n = k * 256 + t;
        if (n < N_NODES) {
            float a = t1[t] / fmaxf((float)hist[t], 1.0f);
            float2 v; v.x = a; v.y = x[n];
            ax[n] = v;
        }
    }
}

// ---- layer 2 FUSED: gather (agg1,x) pairs -> reconstruct h1 rows in-register
// -> LDS tile -> MFMA GEMV -> h2b.
// h1[s][f] = relu(agg1[s]*W1l[f] + b1[f] + x[s]*W1r[f]) — 8 B gathered per edge;
// gather working set = 800 KB (per-XCD-L2 resident). Each 8-lane group owns ONE
// node (2 passes); lane fo covers features fo*8..fo*8+7. Pairs prefetched ahead.
__global__ __launch_bounds__(256) void k_l2f(
    const int* __restrict__ row, const unsigned short* __restrict__ deg,
    const unsigned int* __restrict__ csr,
    const float2* __restrict__ ax,
    const float* __restrict__ W1l, const float* __restrict__ b1,
    const float* __restrict__ W1r,
    const unsigned short* __restrict__ wp, const float* __restrict__ b2,
    unsigned short* __restrict__ h2b) {
    __shared__ unsigned short tile[4][16 * TROW];   // 9 KB
    int wid = threadIdx.x >> 6;
    int w = blockIdx.x * 4 + wid;
    if (w >= N_NODES / 16) return;
    int L = threadIdx.x & 63;
    int fo = L & 7;
    int g  = L >> 3;
    unsigned short* tw = tile[wid];

    // per-lane W1 constants for features fo*8 .. fo*8+7, as float2 pairs
    f2v w1l_[4], w1r_[4], bb_[4];
    {
        const f2v* pl = (const f2v*)(W1l + fo * 8);
        const f2v* pr = (const f2v*)(W1r + fo * 8);
        const f2v* pb = (const f2v*)(b1  + fo * 8);
#pragma unroll
        for (int q = 0; q < 4; q++) { w1l_[q] = pl[q]; w1r_[q] = pr[q]; bb_[q] = pb[q]; }
    }

    int nA = w * 16 + g;
    int nB = nA + 8;
    int r0A = row[nA]; int dnA = (int)deg[nA];
    int r0B = row[nB]; int dnB = (int)deg[nB];

// ds_swizzle BitMode: and=0x18 keeps group base (bits 3-4 within 32-half),
// or=j selects lane j of the group. Pattern must be a Sema-time literal.
#define SWZ(v, j) __builtin_amdgcn_ds_swizzle((v), (((j) << 5) | 0x18))
#define EDGE(j) { \
    unsigned au = (unsigned)SWZ((int)__float_as_uint(pr0.x), j); \
    unsigned xu = (unsigned)SWZ((int)__float_as_uint(pr0.y), j); \
    float a_ = __uint_as_float(au), x_ = __uint_as_float(xu); \
    f2v av; av.x = a_; av.y = a_; \
    f2v xv; xv.x = x_; xv.y = x_; \
    pp0 += max2(av * w1l_[0] + (xv * w1r_[0] + bb_[0])); \
    pp1 += max2(av * w1l_[1] + (xv * w1r_[1] + bb_[1])); \
    pp2 += max2(av * w1l_[2] + (xv * w1r_[2] + bb_[2])); \
    pp3 += max2(av * w1l_[3] + (xv * w1r_[3] + bb_[3])); }
#define REM(j) if ((j) < rem) EDGE(j)

#pragma unroll
    for (int pass = 0; pass < 2; pass++) {
        int r0 = pass ? r0B : r0A;
        int dn = pass ? dnB : dnA;
        int trow = g + 8 * pass;
        int r1 = r0 + dn;
        f2v pp0 = {0.f, 0.f}, pp1 = pp0, pp2 = pp0, pp3 = pp0;
        int base = r0;
        // pipeline startup: pairs for chunk 0, index for chunk 1
        int c0 = max(min(base + fo, r1 - 1), r0);
        unsigned i0 = min((unsigned)csr[c0], (unsigned)(N_NODES - 1));
        float2 pr0 = ax[i0];
        int c1 = max(min(base + 8 + fo, r1 - 1), r0);
        unsigned i1 = min((unsigned)csr[c1], (unsigned)(N_NODES - 1));
        while (base + 8 <= r1) {
            float2 prn = ax[i1];                      // next chunk's pairs
            int c2 = max(min(base + 16 + fo, r1 - 1), r0);
            unsigned i2 = min((unsigned)csr[c2], (unsigned)(N_NODES - 1));
            EDGE(0) EDGE(1) EDGE(2) EDGE(3)
            EDGE(4) EDGE(5) EDGE(6) EDGE(7)
            pr0 = prn; i1 = i2; base += 8;
        }
        int rem = r1 - base;
        if (rem > 0) {
            REM(0) REM(1) REM(2) REM(3)
            REM(4) REM(5) REM(6) REM(7)
        }
        float inv = 1.0f / fmaxf((float)dn, 1.0f);
        f2v iv; iv.x = inv; iv.y = inv;
        pp0 *= iv; pp1 *= iv; pp2 *= iv; pp3 *= iv;
        unsigned w0 = (unsigned)f2bf(pp0.x) | ((unsigned)f2bf(pp0.y) << 16);
        unsigned w1 = (unsigned)f2bf(pp1.x) | ((unsigned)f2bf(pp1.y) << 16);
        unsigned w2 = (unsigned)f2bf(pp2.x) | ((unsigned)f2bf(pp2.y) << 16);
        unsigned w3 = (unsigned)f2bf(pp3.x) | ((unsigned)f2bf(pp3.y) << 16);
        uint4 pk; pk.x = w0; pk.y = w1; pk.z = w2; pk.w = w3;
        *(uint4*)(tw + trow * TROW + fo * 8) = pk;   // full 128B row per group
    }
#undef SWZ
#undef EDGE
#undef REM

    // ---- MFMA phase: A = [agg2 (LDS tile) | root h1 (reconstructed)] ----
    int m = L & 15, q = L >> 4;
    int nrow = w * 16 + m;

    const s8v a0 = *(const s8v*)(tw + m * TROW + q * 8);
    const s8v a1 = *(const s8v*)(tw + m * TROW + 32 + q * 8);

    // reconstruct root h1[nrow] slices: features q*8..+7 and 32+q*8..+7
    float2 axn = ax[nrow];
    union { s8v v; unsigned u[4]; } A2, A3;
    {
        const f2v* l1 = (const f2v*)(W1l + q * 8);
        const f2v* r1p = (const f2v*)(W1r + q * 8);
        const f2v* bp = (const f2v*)(b1 + q * 8);
        const f2v* l2 = (const f2v*)(W1l + 32 + q * 8);
        const f2v* r2p = (const f2v*)(W1r + 32 + q * 8);
        const f2v* b2p = (const f2v*)(b1 + 32 + q * 8);
        f2v av; av.x = axn.x; av.y = axn.x;
        f2v xv; xv.x = axn.y; xv.y = axn.y;
#pragma unroll
        for (int k = 0; k < 4; k++) {
            f2v v1 = max2(av * l1[k] + (xv * r1p[k] + bp[k]));
            f2v v2 = max2(av * l2[k] + (xv * r2p[k] + b2p[k]));
            A2.u[k] = (unsigned)f2bf(v1.x) | ((unsigned)f2bf(v1.y) << 16);
            A3.u[k] = (unsigned)f2bf(v2.x) | ((unsigned)f2bf(v2.y) << 16);
        }
    }
    const s8v a2 = A2.v;
    const s8v a3 = A3.v;

#define LOADB(i) s8v B##i = *(const s8v*)(wp + (i) * 512 + L * 8)
    LOADB(0); LOADB(1); LOADB(2); LOADB(3);
    LOADB(4); LOADB(5); LOADB(6); LOADB(7);
    LOADB(8); LOADB(9); LOADB(10); LOADB(11);
    LOADB(12); LOADB(13); LOADB(14); LOADB(15);
#undef LOADB

    f4v acc0 = {0.f, 0.f, 0.f, 0.f}, acc1 = acc0, acc2 = acc0, acc3 = acc0;
    acc0 = __builtin_amdgcn_mfma_f32_16x16x32_bf16(a0, B0,  acc0, 0, 0, 0);
    acc0 = __builtin_amdgcn_mfma_f32_16x16x32_bf16(a1, B4,  acc0, 0, 0, 0);
    acc0 = __builtin_amdgcn_mfma_f32_16x16x32_bf16(a2, B8,  acc0, 0, 0, 0);
    acc0 = __builtin_amdgcn_mfma_f32_16x16x32_bf16(a3, B12, acc0, 0, 0, 0);
    acc1 = __builtin_amdgcn_mfma_f32_16x16x32_bf16(a0, B1,  acc1, 0, 0, 0);
    acc1 = __builtin_amdgcn_mfma_f32_16x16x32_bf16(a1, B5,  acc1, 0, 0, 0);
    acc1 = __builtin_amdgcn_mfma_f32_16x16x32_bf16(a2, B9,  acc1, 0, 0, 0);
    acc1 = __builtin_amdgcn_mfma_f32_16x16x32_bf16(a3, B13, acc1, 0, 0, 0);
    acc2 = __builtin_amdgcn_mfma_f32_16x16x32_bf16(a0, B2,  acc2, 0, 0, 0);
    acc2 = __builtin_amdgcn_mfma_f32_16x16x32_bf16(a1, B6,  acc2, 0, 0, 0);
    acc2 = __builtin_amdgcn_mfma_f32_16x16x32_bf16(a2, B10, acc2, 0, 0, 0);
    acc2 = __builtin_amdgcn_mfma_f32_16x16x32_bf16(a3, B14, acc2, 0, 0, 0);
    acc3 = __builtin_amdgcn_mfma_f32_16x16x32_bf16(a0, B3,  acc3, 0, 0, 0);
    acc3 = __builtin_amdgcn_mfma_f32_16x16x32_bf16(a1, B7,  acc3, 0, 0, 0);
    acc3 = __builtin_amdgcn_mfma_f32_16x16x32_bf16(a2, B11, acc3, 0, 0, 0);
    acc3 = __builtin_amdgcn_mfma_f32_16x16x32_bf16(a3, B15, acc3, 0, 0, 0);

    int fcol = L & 15;
    float bia0 = b2[fcol], bia1 = b2[16 + fcol], bia2 = b2[32 + fcol], bia3 = b2[48 + fcol];
    int rbase = w * 16 + q * 4;
#pragma unroll
    for (int r = 0; r < 4; r++) {
        size_t o = (size_t)(rbase + r) * 64 + fcol;
        h2b[o]      = f2bf(fmaxf(acc0[r] + bia0, 0.0f));
        h2b[o + 16] = f2bf(fmaxf(acc1[r] + bia1, 0.0f));
        h2b[o + 32] = f2bf(fmaxf(acc2[r] + bia2, 0.0f));
        h2b[o + 48] = f2bf(fmaxf(acc3[r] + bia3, 0.0f));
    }
}

// ---- head: block per graph — pool h2 rows + classify, no global intermediates ----
__global__ __launch_bounds__(256) void k_head(
    const unsigned short* __restrict__ h2b, const int* __restrict__ gstart,
    const float* __restrict__ Wc, const float* __restrict__ bc,
    float* __restrict__ out) {
    __shared__ float part[4][64];
    __shared__ float rowv[64];
    int g = blockIdx.x;
    int wid = threadIdx.x >> 6;
    int f = threadIdx.x & 63;
    int ns = gstart[g], ne = gstart[g + 1];
    float s = 0.0f;
    int n = ns + wid;
    for (; n + 12 < ne; n += 16) {
        float v0 = bf2f(h2b[(size_t)(n)      * 64 + f]);
        float v1 = bf2f(h2b[(size_t)(n + 4)  * 64 + f]);
        float v2 = bf2f(h2b[(size_t)(n + 8)  * 64 + f]);
        float v3 = bf2f(h2b[(size_t)(n + 12) * 64 + f]);
        s += (v0 + v1) + (v2 + v3);
    }
    for (; n < ne; n += 4) s += bf2f(h2b[(size_t)n * 64 + f]);
    part[wid][f] = s;
    __syncthreads();
    if (threadIdx.x < 64) {
        float tot = part[0][f] + part[1][f] + part[2][f] + part[3][f];
        rowv[f] = tot / fmaxf((float)(ne - ns), 1.0f);
    }
    __syncthreads();
    if (threadIdx.x < NCLS) {
        float acc = bc[threadIdx.x];
#pragma unroll
        for (int kk = 0; kk < 64; kk++) acc += rowv[kk] * Wc[kk * NCLS + threadIdx.x];
        out[g * NCLS + threadIdx.x] = acc;
    }
}

extern "C" void kernel_launch(void* const* d_in, const int* in_sizes, int n_in,
                              void* d_out, int out_size, void* d_ws, size_t ws_size,
                              hipStream_t stream) {
    const float* x     = (const float*)d_in[0];
    const int*   eidx  = (const int*)d_in[1];
    const int*   batch = (const int*)d_in[2];
    const float* W1l   = (const float*)d_in[3];
    const float* b1    = (const float*)d_in[4];
    const float* W1r   = (const float*)d_in[5];
    const float* W2l   = (const float*)d_in[6];
    const float* b2    = (const float*)d_in[7];
    const float* W2r   = (const float*)d_in[8];
    const float* Wc    = (const float*)d_in[9];
    const float* bc    = (const float*)d_in[10];
    float* out = (float*)d_out;

    const int* src = eidx;
    const int* dst = eidx + N_EDGES;

    // workspace ≈ 28.6 MB
    char* p = (char*)d_ws;
    unsigned int* bins  = (unsigned int*)p;     p += (size_t)NBKT * CAP * 4;     // 14.0 MB
    float2* ax          = (float2*)p;           p += (size_t)N_NODES * 8;        // 0.80 MB
    unsigned short* h2b = (unsigned short*)p;   p += (size_t)N_NODES * 64 * 2;   // 12.8 MB
    int* row   = (int*)p;                       p += (size_t)(N_NODES + 1) * 4;  // 0.40 MB
    unsigned short* deg = (unsigned short*)p;   p += (size_t)N_NODES * 2;        // 0.20 MB
    int* gcur  = (int*)p;                       p += NBKT * 4;
    int* gstart= (int*)p;                       p += (N_GRAPHS + 1) * 4;
    unsigned short* wp = (unsigned short*)p;    p += 8192 * 2;                   // 16 KB

    k_prep  <<<38, 256, 0, stream>>>(W2l, W2r, wp, batch, gstart, gcur);
    k_binone<<<NB, 256, 0, stream>>>(src, dst, gcur, bins);
    k_build <<<NBKT, 512, 0, stream>>>(gcur, bins, row, deg, x, ax);
    k_l2f   <<<(N_NODES / 16 + 3) / 4, 256, 0, stream>>>(row, deg, bins, ax,
                                                          W1l, b1, W1r, wp, b2, h2b);
    k_head  <<<N_GRAPHS, 256, 0, stream>>>(h2b, gstart, Wc, bc, out);
}